// Round 14
// baseline (200.319 us; speedup 1.0000x reference)
//
#include <hip/hip_runtime.h>
#include <cstdint>
#include <cstddef>

// ---------------------------------------------------------------------------
// LSTM cell, fully fused GEMM+epilogue:
//   gates = [x|h] (2048x4096) · [W_ih|W_hh]^T (8192x4096) + b  -> LSTM math
// R14: 128x256 tile (2m x 4n waves), BK=32, 48 KiB LDS -> 2 blocks/CU.
// LDS re-read traffic drops 1.5x (64 KB/tile vs 96); barrier stalls overlap
// across the two resident blocks. acc 64/lane; launch_bounds(512,4).
// Swizzle for 64-B rows: slot = lq ^ ((row>>1)&3)  (2-way = free).
// ---------------------------------------------------------------------------

typedef __attribute__((ext_vector_type(8))) short bf16x8;
typedef __attribute__((ext_vector_type(4))) float f32x4;

#define GLD_AS1 const __attribute__((address_space(1))) void
#define GLD_AS3 __attribute__((address_space(3))) void

__device__ __forceinline__ void gload_lds16(const void* g, void* l) {
  __builtin_amdgcn_global_load_lds((GLD_AS1*)g, (GLD_AS3*)l, 16, 0, 0);
}

__device__ __forceinline__ unsigned short f2bf(float f) {
  unsigned int u = __float_as_uint(f);
  unsigned int r = 0x7FFFu + ((u >> 16) & 1u);
  return (unsigned short)((u + r) >> 16);
}

__device__ __forceinline__ void barrier_f() {
  asm volatile("" ::: "memory");
  __builtin_amdgcn_s_barrier();
  asm volatile("" ::: "memory");
}

__device__ __forceinline__ float sigm(float x) {
  return __fdividef(1.0f, 1.0f + __expf(-x));
}
__device__ __forceinline__ float ftanh(float x) {
  float xc = fminf(fmaxf(x, -9.0f), 9.0f);
  float e = __expf(2.0f * xc);
  return 1.0f - __fdividef(2.0f, e + 1.0f);
}

// ---- merged pack: fp32 (rows x 2048) -> bf16 (rows x 4096 at col off) -----
__global__ __launch_bounds__(256) void cvt_all(const float* __restrict__ x,
                                               const float* __restrict__ h,
                                               const float* __restrict__ Wih,
                                               const float* __restrict__ Whh,
                                               unsigned short* __restrict__ Abf,
                                               unsigned short* __restrict__ Wbf) {
  int bid = blockIdx.x;
  const float* src; unsigned short* dst; int col_off; int base;
  if (bid < 4096)        { src = x;   dst = Abf; col_off = 0;    base = bid; }
  else if (bid < 8192)   { src = h;   dst = Abf; col_off = 2048; base = bid - 4096; }
  else if (bid < 24576)  { src = Wih; dst = Wbf; col_off = 0;    base = bid - 8192; }
  else                   { src = Whh; dst = Wbf; col_off = 2048; base = bid - 24576; }
  int i = base * 256 + threadIdx.x;
  int flat = i << 2;
  int r = flat >> 11;
  int c = flat & 2047;
  float4 v = *(const float4*)(src + flat);
  ushort4 o;
  o.x = f2bf(v.x); o.y = f2bf(v.y); o.z = f2bf(v.z); o.w = f2bf(v.w);
  *(ushort4*)(dst + (((size_t)r) << 12) + col_off + c) = o;
}

// ---- fused 128x256 BK=32 bf16 GEMM + LSTM epilogue -------------------------
// BM=128 M-rows, "BN=256" = 4 gates x 64 h-cols (gate-permuted W rows).
// Local B row L (0..255): W row = ((L>>4)&3)*2048 + h0 + 16*(L>>6) + (L&15).
// LDS 48 KiB: per buf {A 128x32 (8KB) | B 256x32 (16KB)}, row = 64 B.
// Swizzle: 16B-slot p at row r holds global slot p ^ ((r>>1)&3); staging
// source pre-swizzled, reads use ce = (lq ^ ((l15>>1)&3))*8 (2-way, free).
// Per tile: vmcnt(3)+BAR | 8 ds_read_b128 | 16 MFMA | BAR | stage(t+2).
__global__ __launch_bounds__(512, 4) void gemm_lstm(
    const unsigned short* __restrict__ A,   // [2048][4096] bf16 = [x|h]
    const unsigned short* __restrict__ W,   // [8192][4096] bf16 = [Wih|Whh]
    const float* __restrict__ b_ih, const float* __restrict__ b_hh,
    const float* __restrict__ C_prev,       // [2048][2048] fp32
    float* __restrict__ out)                // 6 x [2048][2048] fp32
{
  constexpr int K = 4096;
  constexpr int BK = 32;
  constexpr int NT = K / BK;                // 128 K-tiles
  // [buf][A: 128*32 | B: 256*32] ushorts
  __shared__ alignas(16) unsigned short lds[2][(128 + 256) * 32];  // 48 KiB

  // 512 blocks: xc = b&7 (XCD), ii = b>>3: bm = ii&15, h-slab = ii>>4
  int b  = blockIdx.x;
  int xc = b & 7, ii = b >> 3;
  int bm = (ii & 15) * 128;                 // A row base
  int h0 = (xc * 4 + (ii >> 4)) * 64;       // h-tile base

  int tid  = threadIdx.x;
  int lane = tid & 63;
  int w    = tid >> 6;        // 0..7
  int wm   = w >> 2;          // 0..1 -> M half (64 rows)
  int wn   = w & 3;           // 0..3 -> N quarter (64 cols = 4 gates x 16 h)
  int l15  = lane & 15;
  int lq   = lane >> 4;       // 0..3 k-slot

  // read swizzle: 16B slot for k-group lq at row r: lq ^ ((r>>1)&3);
  // rows differ by multiples of 16 -> per-lane constant:
  int ce = (lq ^ ((l15 >> 1) & 3)) * 8;     // ushort offset within 32-elem row

  // staging: lane l -> row r = l>>2, slot p = l&3; source col pre-swizzled
  int sr = lane >> 2;                       // 0..15
  int scol = ((lane & 3) ^ ((sr >> 1) & 3)) * 8;   // ushort (8 bf16 = 16 B)

  // A: wave w stages chunk w = A rows bm + 16w + sr
  const unsigned short* gA = A + (size_t)(bm + 16 * w + sr) * K + scol;
  // B: wave w stages local rows {32w+sr', 32w+16+sr'}; W row for chunk c'
  //    (c'=0,1): (2*(w&1)+c')*2048 + h0 + 16*(w>>1) + sr
  const unsigned short* gB0 =
      W + (size_t)((2 * (w & 1)) * 2048 + h0 + 16 * (w >> 1) + sr) * K + scol;
  const unsigned short* gB1 = gB0 + (size_t)2048 * K;   // c'=1

  f32x4 acc[4][4] = {};                     // [mt][gate]

  auto stage = [&](int t) {                 // 3 gloads: 1 A + 2 B
    unsigned short* base = lds[t & 1];
    int k0 = t * BK;
    gload_lds16(gA + k0, base + w * 512 + 8 * lane);
    gload_lds16(gB0 + k0, base + 4096 + (32 * w) * 32 + 8 * lane);
    gload_lds16(gB1 + k0, base + 4096 + (32 * w + 16) * 32 + 8 * lane);
  };

  // prologue
  stage(0); stage(1);

  bf16x8 af[4], bg[4];

  for (int t = 0; t < NT; ++t) {
    if (t < NT - 1) asm volatile("s_waitcnt vmcnt(3)" ::: "memory");
    else            asm volatile("s_waitcnt vmcnt(0)" ::: "memory");
    barrier_f();

    const unsigned short* Ab = lds[t & 1];
    const unsigned short* Bb = lds[t & 1] + 4096;

    // 8 ds_read_b128: A m0-3 (rows wm*64+mt*16+l15), B g0-3 (rows 64wn+16g+l15)
#pragma unroll
    for (int mt = 0; mt < 4; ++mt)
      af[mt] = *(const bf16x8*)&Ab[(wm * 64 + mt * 16 + l15) * 32 + ce];
#pragma unroll
    for (int g = 0; g < 4; ++g)
      bg[g] = *(const bf16x8*)&Bb[(wn * 64 + g * 16 + l15) * 32 + ce];

    // 16 MFMA
    __builtin_amdgcn_s_setprio(1);
#pragma unroll
    for (int mt = 0; mt < 4; ++mt)
#pragma unroll
      for (int g = 0; g < 4; ++g)
        acc[mt][g] = __builtin_amdgcn_mfma_f32_16x16x32_bf16(af[mt], bg[g], acc[mt][g], 0, 0, 0);
    __builtin_amdgcn_s_setprio(0);

    barrier_f();                            // all waves' reads of buf done
    if (t + 2 < NT) stage(t + 2);           // overwrite buf[t&1] safely
  }

  // ---- fused LSTM epilogue ------------------------------------------------
  // gate g; h-col = h0 + 16*wn + l15; row = bm + wm*64 + mt*16 + lq*4 + j.
  int hcol = h0 + wn * 16 + l15;
  float cb0 = b_ih[hcol]        + b_hh[hcol];
  float cb1 = b_ih[2048 + hcol] + b_hh[2048 + hcol];
  float cb2 = b_ih[4096 + hcol] + b_hh[4096 + hcol];
  float cb3 = b_ih[6144 + hcol] + b_hh[6144 + hcol];
  constexpr size_t SEC = (size_t)2048 * 2048;
#pragma unroll
  for (int mt = 0; mt < 4; ++mt) {
    int row0 = bm + wm * 64 + mt * 16 + lq * 4;
#pragma unroll
    for (int j = 0; j < 4; ++j) {
      size_t off = (size_t)(row0 + j) * 2048 + hcol;
      float I = sigm(acc[mt][0][j] + cb0);
      float F = sigm(acc[mt][1][j] + cb1);
      float G = ftanh(acc[mt][2][j] + cb2);
      float O = sigm(acc[mt][3][j] + cb3);
      float C = F * C_prev[off] + I * G;
      float H = O * ftanh(C);
      out[0 * SEC + off] = H;
      out[1 * SEC + off] = C;
      out[2 * SEC + off] = F;
      out[3 * SEC + off] = I;
      out[4 * SEC + off] = G;
      out[5 * SEC + off] = O;
    }
  }
}

// ---------------------------------------------------------------------------
extern "C" void kernel_launch(void* const* d_in, const int* in_sizes, int n_in,
                              void* d_out, int out_size, void* d_ws, size_t ws_size,
                              hipStream_t stream) {
  const float* x   = (const float*)d_in[0];
  const float* h   = (const float*)d_in[1];
  const float* Cp  = (const float*)d_in[2];
  const float* Wih = (const float*)d_in[3];
  const float* bih = (const float*)d_in[4];
  const float* Whh = (const float*)d_in[5];
  const float* bhh = (const float*)d_in[6];
  float* out = (float*)d_out;

  uint8_t* ws = (uint8_t*)d_ws;
  unsigned short* Abf  = (unsigned short*)ws;                          // 16 MiB
  unsigned short* Wbf  = (unsigned short*)(ws + (size_t)(16u << 20));  // 64 MiB

  cvt_all<<<40960, 256, 0, stream>>>(x, h, Wih, Whh, Abf, Wbf);
  gemm_lstm<<<512, 512, 0, stream>>>(Abf, Wbf, bih, bhh, Cp, out);
}

// Round 15
// 168.939 us; speedup vs baseline: 1.1857x; 1.1857x over previous
//
#include <hip/hip_runtime.h>
#include <cstdint>
#include <cstddef>

// ---------------------------------------------------------------------------
// LSTM cell, fully fused GEMM+epilogue (CHAMPION, R13 revert):
//   gates = [x|h] (2048x4096) · [W_ih|W_hh]^T (8192x4096) + b  -> LSTM math
// cvt (HBM-roofline) -> 256² BK=64 bf16 MFMA GEMM (R6 K-loop schedule,
// both-sides XOR swizzle, XCD slab mapping) -> peeled last tile with C_prev
// DMA'd to LDS buf0 (zero VGPR) -> fused per-lane LSTM epilogue.
// ---------------------------------------------------------------------------

typedef __attribute__((ext_vector_type(8))) short bf16x8;
typedef __attribute__((ext_vector_type(4))) float f32x4;

#define GLD_AS1 const __attribute__((address_space(1))) void
#define GLD_AS3 __attribute__((address_space(3))) void

__device__ __forceinline__ void gload_lds16(const void* g, void* l) {
  __builtin_amdgcn_global_load_lds((GLD_AS1*)g, (GLD_AS3*)l, 16, 0, 0);
}

__device__ __forceinline__ unsigned short f2bf(float f) {
  unsigned int u = __float_as_uint(f);
  unsigned int r = 0x7FFFu + ((u >> 16) & 1u);
  return (unsigned short)((u + r) >> 16);
}

__device__ __forceinline__ void barrier_f() {
  asm volatile("" ::: "memory");
  __builtin_amdgcn_s_barrier();
  asm volatile("" ::: "memory");
}

__device__ __forceinline__ float sigm(float x) {
  return __fdividef(1.0f, 1.0f + __expf(-x));
}
__device__ __forceinline__ float ftanh(float x) {
  float xc = fminf(fmaxf(x, -9.0f), 9.0f);
  float e = __expf(2.0f * xc);
  return 1.0f - __fdividef(2.0f, e + 1.0f);
}

// ---- merged pack: fp32 (rows x 2048) -> bf16 (rows x 4096 at col off) -----
__global__ __launch_bounds__(256) void cvt_all(const float* __restrict__ x,
                                               const float* __restrict__ h,
                                               const float* __restrict__ Wih,
                                               const float* __restrict__ Whh,
                                               unsigned short* __restrict__ Abf,
                                               unsigned short* __restrict__ Wbf) {
  int bid = blockIdx.x;
  const float* src; unsigned short* dst; int col_off; int base;
  if (bid < 4096)        { src = x;   dst = Abf; col_off = 0;    base = bid; }
  else if (bid < 8192)   { src = h;   dst = Abf; col_off = 2048; base = bid - 4096; }
  else if (bid < 24576)  { src = Wih; dst = Wbf; col_off = 0;    base = bid - 8192; }
  else                   { src = Whh; dst = Wbf; col_off = 2048; base = bid - 24576; }
  int i = base * 256 + threadIdx.x;
  int flat = i << 2;
  int r = flat >> 11;
  int c = flat & 2047;
  float4 v = *(const float4*)(src + flat);
  ushort4 o;
  o.x = f2bf(v.x); o.y = f2bf(v.y); o.z = f2bf(v.z); o.w = f2bf(v.w);
  *(ushort4*)(dst + (((size_t)r) << 12) + col_off + c) = o;
}

// ---- fused 256² bf16 GEMM + LSTM epilogue ----------------------------------
// BM=256, "BN=256" = 4 gates x 64 h-cols (gate-permuted W rows), BK=64.
// LDS 128 KiB: lds[buf2][part4][128*64]; swizzle colbyte ^= (localrow&7)<<4,
// pre-swizzled global SOURCE + swizzled fragment READ (both-sides).
// K-loop: boundary vm(8)+BAR | 24 ds_reads | P0P1(32 MFMA) | BAR |
// stageB(t+2) | P2(16) | BAR | stageA(t+2) | P3(16).
// Peel (t=63, reads buf1): C_prev 64KB DMA'd into buf0 + biases in 4 VGPRs.
__global__ __launch_bounds__(512, 2) void gemm_lstm(
    const unsigned short* __restrict__ A,   // [2048][4096] bf16 = [x|h]
    const unsigned short* __restrict__ W,   // [8192][4096] bf16 = [Wih|Whh]
    const float* __restrict__ b_ih, const float* __restrict__ b_hh,
    const float* __restrict__ C_prev,       // [2048][2048] fp32
    float* __restrict__ out)                // 6 x [2048][2048] fp32
{
  constexpr int K = 4096;
  constexpr int BK = 64;
  constexpr int NT = K / BK;                // 64 K-tiles
  __shared__ alignas(16) unsigned short lds[2][4][128 * 64];  // 128 KiB

  // XCD slab: xc owns 4 h-tiles x all 8 bm-tiles
  int b  = blockIdx.x;
  int xc = b & 7, ii = b >> 3;
  int bm = (ii & 7) * 256;
  int h0 = (xc * 4 + (ii >> 3)) * 64;

  int tid  = threadIdx.x;
  int lane = tid & 63;
  int w    = tid >> 6;        // 0..7
  int wm   = w >> 2;          // A-half
  int wn   = w & 3;           // B-part wn>>1, sub-row (wn&1)*64
  int l15  = lane & 15;
  int lq   = lane >> 4;

  // swizzled fragment col (elements) for kq=0,1
  int ce0 = ((lq * 16) ^ ((l15 & 7) << 4)) >> 1;
  int ce1 = ((64 + lq * 16) ^ ((l15 & 7) << 4)) >> 1;

  // staging: wave w writes local rows 16w..16w+15 of a part;
  // pre-swizzled source: row_local = 16w + (lane>>3), col = ((l&7)^(l>>3))*8
  int srow_s = lane >> 3;
  int scol = ((lane & 7) ^ (lane >> 3)) * 8;
  const unsigned short* gA = A + (size_t)(bm + 16 * w + srow_s) * K + scol;
  const unsigned short* gB0 =
      W + (size_t)((w & 3) * 2048 + h0 + 16 * (w >> 2) + srow_s) * K + scol;

  f32x4 acc[8][4] = {};

  auto stageA = [&](int t, int hh) {
    unsigned short* l0 = &lds[t & 1][hh][w * 1024];
    const unsigned short* g = gA + (size_t)hh * 128 * K + t * BK;
    gload_lds16(g, l0);
    gload_lds16(g + (size_t)8 * K, l0 + 512);
  };
  auto stageB = [&](int t, int hh) {
    unsigned short* l0 = &lds[t & 1][2 + hh][w * 1024];
    const unsigned short* g = gB0 + (size_t)hh * 32 * K + t * BK;
    gload_lds16(g, l0);
    gload_lds16(g + (size_t)8 * K, l0 + 512);
  };

  int hcol = h0 + wn * 16 + l15;
  constexpr size_t SEC = (size_t)2048 * 2048;

  // ---- prologue: tiles 0 and 1 fully staged (16 loads/thread)
  stageA(0, 0); stageA(0, 1); stageB(0, 0); stageB(0, 1);
  stageA(1, 0); stageA(1, 1); stageB(1, 0); stageB(1, 1);

  bf16x8 af[4][2], af2[4][2], bf01[2][2], bf23[2][2];

  for (int t = 0; t < NT - 1; ++t) {
    asm volatile("s_waitcnt vmcnt(8)" ::: "memory");
    barrier_f();

    const unsigned short* Ab = lds[t & 1][wm];
    const unsigned short* Bb = lds[t & 1][2 + (wn >> 1)];
    int brow = (wn & 1) * 64;

    // 24 ds_reads up front (compiler inserts counted lgkmcnt before MFMAs)
#pragma unroll
    for (int mt = 0; mt < 4; ++mt) {
      af[mt][0] = *(const bf16x8*)&Ab[(mt * 16 + l15) * 64 + ce0];
      af[mt][1] = *(const bf16x8*)&Ab[(mt * 16 + l15) * 64 + ce1];
    }
#pragma unroll
    for (int nt = 0; nt < 2; ++nt) {
      bf01[nt][0] = *(const bf16x8*)&Bb[(brow + nt * 16 + l15) * 64 + ce0];
      bf01[nt][1] = *(const bf16x8*)&Bb[(brow + nt * 16 + l15) * 64 + ce1];
      bf23[nt][0] = *(const bf16x8*)&Bb[(brow + (2 + nt) * 16 + l15) * 64 + ce0];
      bf23[nt][1] = *(const bf16x8*)&Bb[(brow + (2 + nt) * 16 + l15) * 64 + ce1];
    }
#pragma unroll
    for (int mt = 0; mt < 4; ++mt) {
      af2[mt][0] = *(const bf16x8*)&Ab[(64 + mt * 16 + l15) * 64 + ce0];
      af2[mt][1] = *(const bf16x8*)&Ab[(64 + mt * 16 + l15) * 64 + ce1];
    }

    // P0+P1: m0-3 x n0-3 (32 MFMA)
    __builtin_amdgcn_s_setprio(1);
#pragma unroll
    for (int mt = 0; mt < 4; ++mt)
#pragma unroll
      for (int nt = 0; nt < 2; ++nt) {
        acc[mt][nt] = __builtin_amdgcn_mfma_f32_16x16x32_bf16(af[mt][0], bf01[nt][0], acc[mt][nt], 0, 0, 0);
        acc[mt][nt] = __builtin_amdgcn_mfma_f32_16x16x32_bf16(af[mt][1], bf01[nt][1], acc[mt][nt], 0, 0, 0);
        acc[mt][2 + nt] = __builtin_amdgcn_mfma_f32_16x16x32_bf16(af[mt][0], bf23[nt][0], acc[mt][2 + nt], 0, 0, 0);
        acc[mt][2 + nt] = __builtin_amdgcn_mfma_f32_16x16x32_bf16(af[mt][1], bf23[nt][1], acc[mt][2 + nt], 0, 0, 0);
      }
    __builtin_amdgcn_s_setprio(0);

    barrier_f();  // all waves' A/B reads of this tile done
    if (t + 2 < NT) { stageB(t + 2, 0); stageB(t + 2, 1); }

    // P2: m4-7 x n2-3 (16 MFMA)
    __builtin_amdgcn_s_setprio(1);
#pragma unroll
    for (int mt = 0; mt < 4; ++mt)
#pragma unroll
      for (int nt = 0; nt < 2; ++nt) {
        acc[4 + mt][2 + nt] = __builtin_amdgcn_mfma_f32_16x16x32_bf16(af2[mt][0], bf23[nt][0], acc[4 + mt][2 + nt], 0, 0, 0);
        acc[4 + mt][2 + nt] = __builtin_amdgcn_mfma_f32_16x16x32_bf16(af2[mt][1], bf23[nt][1], acc[4 + mt][2 + nt], 0, 0, 0);
      }
    __builtin_amdgcn_s_setprio(0);

    barrier_f();  // all waves' A reads done
    if (t + 2 < NT) { stageA(t + 2, 0); stageA(t + 2, 1); }

    // P3: m4-7 x n0-1 (16 MFMA)
    __builtin_amdgcn_s_setprio(1);
#pragma unroll
    for (int mt = 0; mt < 4; ++mt)
#pragma unroll
      for (int nt = 0; nt < 2; ++nt) {
        acc[4 + mt][nt] = __builtin_amdgcn_mfma_f32_16x16x32_bf16(af2[mt][0], bf01[nt][0], acc[4 + mt][nt], 0, 0, 0);
        acc[4 + mt][nt] = __builtin_amdgcn_mfma_f32_16x16x32_bf16(af2[mt][1], bf01[nt][1], acc[4 + mt][nt], 0, 0, 0);
      }
    __builtin_amdgcn_s_setprio(0);
  }

  // ================= peeled last tile (t = NT-1 = 63, reads buf 1) ========
  float cb0, cb1, cb2, cb3;
  {
    asm volatile("s_waitcnt vmcnt(0)" ::: "memory");
    barrier_f();   // buf0's last readers (tile 62) are done -> buf0 is free

    // C_prev 64KB -> LDS buf0 via DMA (zero VGPR); lands under peel compute.
    float* cp_lds = (float*)&lds[0][0][0];
    const float* gC =
        C_prev + (size_t)(bm + 4 * w + (lane >> 4)) * 2048 + h0 + (lane & 15) * 4;
#pragma unroll
    for (int i = 0; i < 8; ++i)
      gload_lds16(gC + (size_t)(32 * i) * 2048, cp_lds + 2048 * i + 256 * w);

    // biases: 4 VGPRs only
    cb0 = b_ih[hcol]        + b_hh[hcol];
    cb1 = b_ih[2048 + hcol] + b_hh[2048 + hcol];
    cb2 = b_ih[4096 + hcol] + b_hh[4096 + hcol];
    cb3 = b_ih[6144 + hcol] + b_hh[6144 + hcol];

    const unsigned short* Ab = lds[1][wm];
    const unsigned short* Bb = lds[1][2 + (wn >> 1)];
    int brow = (wn & 1) * 64;

#pragma unroll
    for (int mt = 0; mt < 4; ++mt) {
      af[mt][0] = *(const bf16x8*)&Ab[(mt * 16 + l15) * 64 + ce0];
      af[mt][1] = *(const bf16x8*)&Ab[(mt * 16 + l15) * 64 + ce1];
    }
#pragma unroll
    for (int nt = 0; nt < 2; ++nt) {
      bf01[nt][0] = *(const bf16x8*)&Bb[(brow + nt * 16 + l15) * 64 + ce0];
      bf01[nt][1] = *(const bf16x8*)&Bb[(brow + nt * 16 + l15) * 64 + ce1];
      bf23[nt][0] = *(const bf16x8*)&Bb[(brow + (2 + nt) * 16 + l15) * 64 + ce0];
      bf23[nt][1] = *(const bf16x8*)&Bb[(brow + (2 + nt) * 16 + l15) * 64 + ce1];
    }
#pragma unroll
    for (int mt = 0; mt < 4; ++mt) {
      af2[mt][0] = *(const bf16x8*)&Ab[(64 + mt * 16 + l15) * 64 + ce0];
      af2[mt][1] = *(const bf16x8*)&Ab[(64 + mt * 16 + l15) * 64 + ce1];
    }

    // all 64 MFMA (C_prev DMA drains underneath)
    __builtin_amdgcn_s_setprio(1);
#pragma unroll
    for (int mt = 0; mt < 4; ++mt)
#pragma unroll
      for (int nt = 0; nt < 2; ++nt) {
        acc[mt][nt] = __builtin_amdgcn_mfma_f32_16x16x32_bf16(af[mt][0], bf01[nt][0], acc[mt][nt], 0, 0, 0);
        acc[mt][nt] = __builtin_amdgcn_mfma_f32_16x16x32_bf16(af[mt][1], bf01[nt][1], acc[mt][nt], 0, 0, 0);
        acc[mt][2 + nt] = __builtin_amdgcn_mfma_f32_16x16x32_bf16(af[mt][0], bf23[nt][0], acc[mt][2 + nt], 0, 0, 0);
        acc[mt][2 + nt] = __builtin_amdgcn_mfma_f32_16x16x32_bf16(af[mt][1], bf23[nt][1], acc[mt][2 + nt], 0, 0, 0);
      }
#pragma unroll
    for (int mt = 0; mt < 4; ++mt)
#pragma unroll
      for (int nt = 0; nt < 2; ++nt) {
        acc[4 + mt][2 + nt] = __builtin_amdgcn_mfma_f32_16x16x32_bf16(af2[mt][0], bf23[nt][0], acc[4 + mt][2 + nt], 0, 0, 0);
        acc[4 + mt][2 + nt] = __builtin_amdgcn_mfma_f32_16x16x32_bf16(af2[mt][1], bf23[nt][1], acc[4 + mt][2 + nt], 0, 0, 0);
        acc[4 + mt][nt] = __builtin_amdgcn_mfma_f32_16x16x32_bf16(af2[mt][0], bf01[nt][0], acc[4 + mt][nt], 0, 0, 0);
        acc[4 + mt][nt] = __builtin_amdgcn_mfma_f32_16x16x32_bf16(af2[mt][1], bf01[nt][1], acc[4 + mt][nt], 0, 0, 0);
      }
    __builtin_amdgcn_s_setprio(0);

    // all C_prev DMA complete across waves
    asm volatile("s_waitcnt vmcnt(0)" ::: "memory");
    barrier_f();
  }

  // ---- unified, temporally-tight epilogue (cp from LDS, conflict-free) ---
  {
    const float* cp_lds = (const float*)&lds[0][0][0];
    int lcol = wn * 16 + l15;
#pragma unroll
    for (int mt = 0; mt < 8; ++mt) {
      int lrow0 = wm * 128 + mt * 16 + lq * 4;
      int row0 = bm + lrow0;
#pragma unroll
      for (int j = 0; j < 4; ++j) {
        size_t off = (size_t)(row0 + j) * 2048 + hcol;
        float cpv = cp_lds[(lrow0 + j) * 64 + lcol];
        float I = sigm(acc[mt][0][j] + cb0);
        float F = sigm(acc[mt][1][j] + cb1);
        float G = ftanh(acc[mt][2][j] + cb2);
        float O = sigm(acc[mt][3][j] + cb3);
        float C = F * cpv + I * G;
        float H = O * ftanh(C);
        out[0 * SEC + off] = H;
        out[1 * SEC + off] = C;
        out[2 * SEC + off] = F;
        out[3 * SEC + off] = I;
        out[4 * SEC + off] = G;
        out[5 * SEC + off] = O;
      }
    }
  }
}

// ---------------------------------------------------------------------------
extern "C" void kernel_launch(void* const* d_in, const int* in_sizes, int n_in,
                              void* d_out, int out_size, void* d_ws, size_t ws_size,
                              hipStream_t stream) {
  const float* x   = (const float*)d_in[0];
  const float* h   = (const float*)d_in[1];
  const float* Cp  = (const float*)d_in[2];
  const float* Wih = (const float*)d_in[3];
  const float* bih = (const float*)d_in[4];
  const float* Whh = (const float*)d_in[5];
  const float* bhh = (const float*)d_in[6];
  float* out = (float*)d_out;

  uint8_t* ws = (uint8_t*)d_ws;
  unsigned short* Abf  = (unsigned short*)ws;                          // 16 MiB
  unsigned short* Wbf  = (unsigned short*)(ws + (size_t)(16u << 20));  // 64 MiB

  cvt_all<<<40960, 256, 0, stream>>>(x, h, Wih, Whh, Abf, Wbf);
  gemm_lstm<<<256, 512, 0, stream>>>(Abf, Wbf, bih, bhh, Cp, out);
}